// Round 1
// 380.654 us; speedup vs baseline: 1.0476x; 1.0476x over previous
//
#include <hip/hip_runtime.h>
#include <math.h>

// GroupSorter: B=512 groups, N=64 rows/group, C=1024 features, fp32.
// rel[n] = mean_m gn[n]·gn[m] = gn[n]·(Σ_m gn[m]/N) — collapsed to one
// weighted column-sum + one dot per row. fp64 accumulation so the sort order
// matches the fp32 reference (absmax 0 requires identical permutation).
//
// R3: single-read register-resident version. R2 read feats 4× (norms, colsum,
// rel, scatter); with 2 blocks/CU the per-XCD read footprint (16 MB) blows the
// 4 MB L2, so re-reads went to L3/HBM — rocprof showed the kernel still well
// above its 61 µs BW floor while harness fills (163 µs each) dominate dur_us.
// Now each thread holds its group slice (16 float4 = 64 VGPR) for the whole
// kernel: one global read pass, both output halves written once (NT stores).
// All reductions (sumsq, colsum, rel) run out of registers + LDS.

constexpr int Bq = 512;
constexpr int Nq = 64;
constexpr int Cq = 1024;
constexpr int C4 = Cq / 4;            // 256 float4 per row
constexpr int G4 = Nq * C4;           // 16384 float4 per group
constexpr int OUT_HALF4 = Bq * G4;    // float4 offset of out_input half

typedef float f4 __attribute__((ext_vector_type(4)));

__global__ __launch_bounds__(1024)
void group_sorter_kernel(const float* __restrict__ feats, float* __restrict__ out) {
    __shared__ double sp[4][C4][4];   // colsum partials: [part][col4][comp] = 32 KB
    __shared__ double red[4][16][4];  // per-row wave partials: [part][row][wave] = 2 KB
    __shared__ float  s_lds[Cq];      // fp32 weighted column sum (4 KB)
    __shared__ double rnorm[Nq];      // 1/max(||g_n||, 1e-12)
    __shared__ double rel[Nq];        // relation score (×N scale: order-preserving)
    __shared__ int    dst_row[Nq];    // output position of source row n

    const int b    = blockIdx.x;
    const int t    = threadIdx.x;
    const int lane = t & 63;
    const int part = t >> 8;          // 0..3 -> owns rows part*16 .. part*16+15
    const int w4   = (t >> 6) & 3;    // wave index within part
    const int c4   = t & 255;         // float4 column

    const f4* __restrict__ g4 = reinterpret_cast<const f4*>(feats) + (size_t)b * G4;
    f4* __restrict__ os = reinterpret_cast<f4*>(out) + (size_t)b * G4;              // out_sorted
    f4* __restrict__ oi = reinterpret_cast<f4*>(out) + OUT_HALF4 + (size_t)b * G4;  // out_input

    f4 v[16];                         // this thread's slice: rows part*16+mm, col c4

    // ---- Load once (coalesced: 1 KB/wave/row) + fused out_input NT copy ------
    #pragma unroll
    for (int mm = 0; mm < 16; ++mm) {
        const int m = part * 16 + mm;
        v[mm] = g4[m * C4 + c4];
        __builtin_nontemporal_store(v[mm], &oi[m * C4 + c4]);
    }

    // ---- Row sum-squares: per-thread fp64 partial -> wave tree -> LDS --------
    #pragma unroll
    for (int mm = 0; mm < 16; ++mm) {
        f4 x = v[mm];
        double acc = (double)x.x * x.x + (double)x.y * x.y
                   + (double)x.z * x.z + (double)x.w * x.w;
        #pragma unroll
        for (int off = 32; off > 0; off >>= 1) acc += __shfl_xor(acc, off, 64);
        if (lane == 0) red[part][mm][w4] = acc;
    }
    __syncthreads();
    if (t < Nq) {
        const int p = t >> 4, r = t & 15;
        double s = red[p][r][0] + red[p][r][1] + red[p][r][2] + red[p][r][3];
        rnorm[t] = 1.0 / fmax(sqrt(s), 1e-12);
    }
    __syncthreads();

    // ---- s[c] = Σ_m g[m][c]·rnorm[m] — from registers, 4-way part split ------
    {
        double s0 = 0, s1 = 0, s2 = 0, s3 = 0;
        #pragma unroll
        for (int mm = 0; mm < 16; ++mm) {
            f4 x = v[mm];
            double rn = rnorm[part * 16 + mm];
            s0 += (double)x.x * rn; s1 += (double)x.y * rn;
            s2 += (double)x.z * rn; s3 += (double)x.w * rn;
        }
        sp[part][c4][0] = s0; sp[part][c4][1] = s1;
        sp[part][c4][2] = s2; sp[part][c4][3] = s3;
    }
    __syncthreads();
    {   // reduce the 4 partials; thread t owns column (t>>2, comp t&3)
        const int cc = t >> 2, comp = t & 3;
        double sum = sp[0][cc][comp] + sp[1][cc][comp]
                   + sp[2][cc][comp] + sp[3][cc][comp];
        s_lds[cc * 4 + comp] = (float)sum;
    }
    __syncthreads();

    // ---- rel[n] = (g[n]·s)·rnorm[n] — from registers ------------------------
    {
        const f4* s4 = reinterpret_cast<const f4*>(s_lds);
        f4 sv = s4[c4];               // 16B/lane contiguous: conflict-free
        #pragma unroll
        for (int mm = 0; mm < 16; ++mm) {
            f4 x = v[mm];
            double p = (double)x.x * sv.x + (double)x.y * sv.y
                     + (double)x.z * sv.z + (double)x.w * sv.w;
            #pragma unroll
            for (int off = 32; off > 0; off >>= 1) p += __shfl_xor(p, off, 64);
            if (lane == 0) red[part][mm][w4] = p;
        }
    }
    __syncthreads();
    if (t < Nq) {
        const int p = t >> 4, r = t & 15;
        double s = red[p][r][0] + red[p][r][1] + red[p][r][2] + red[p][r][3];
        rel[t] = s * rnorm[t];
    }
    __syncthreads();

    // ---- Ranks: stable descending count (ties -> lower index first) ----------
    if (t < Nq) {
        double mine = rel[t];
        int r = 0;
        for (int m = 0; m < Nq; ++m) {
            double o = rel[m];
            r += (o > mine) || (o == mine && m < t);
        }
        dst_row[t] = r;
    }
    __syncthreads();

    // ---- Sorted scatter straight from registers (row-coalesced NT stores) ----
    #pragma unroll
    for (int mm = 0; mm < 16; ++mm) {
        const int dr = dst_row[part * 16 + mm];
        __builtin_nontemporal_store(v[mm], &os[dr * C4 + c4]);
    }
}

extern "C" void kernel_launch(void* const* d_in, const int* in_sizes, int n_in,
                              void* d_out, int out_size, void* d_ws, size_t ws_size,
                              hipStream_t stream) {
    const float* feats = (const float*)d_in[0];
    float* out = (float*)d_out;
    // labels (d_in[1]) encode the static contiguous-uniform grouping; unused.
    hipLaunchKernelGGL(group_sorter_kernel, dim3(Bq), dim3(1024), 0, stream,
                       feats, out);
}